// Round 25
// baseline (236.877 us; speedup 1.0000x reference)
//
#include <hip/hip_runtime.h>
#include <hip/hip_bf16.h>
#include <cstdint>

#define NB 4
#define NS 2048
#define ND 1024
#define NH 16
#define NDH 64
#define NM (NB*NS)       // 8192
#define N3D (3*ND)       // 3072

typedef __attribute__((ext_vector_type(8))) short short8;
typedef __attribute__((ext_vector_type(4))) float f32x4;
typedef __attribute__((ext_vector_type(4))) unsigned short us4;
typedef __attribute__((ext_vector_type(4))) unsigned int uint4v;

__device__ __forceinline__ float bf2f(unsigned short u) {
  unsigned int i = ((unsigned int)u) << 16;
  return __builtin_bit_cast(float, i);
}
__device__ __forceinline__ unsigned short f2bf(float f) {
  unsigned int i = __builtin_bit_cast(unsigned int, f);
  i = (i + 0x7FFFu + ((i >> 16) & 1u)) >> 16;
  return (unsigned short)i;
}
// packed 2x bf16 (RNE) from two f32 — T12 recipe, no builtin on gfx950
__device__ __forceinline__ unsigned int cvtpk_bf16(float lo, float hi) {
  unsigned int r;
  asm("v_cvt_pk_bf16_f32 %0, %1, %2" : "=v"(r) : "v"(lo), "v"(hi));
  return r;
}

#define GLD16(g, l) __builtin_amdgcn_global_load_lds( \
    (__attribute__((address_space(1))) void*)(void*)(g), \
    (__attribute__((address_space(3))) void*)(l), 16, 0, 0)

#define QSCALE_F (0.125f * 1.44269504f)   // exp2-domain attention scale

// ------------------------------------------------------------ f32 -> bf16 cast
__global__ __launch_bounds__(256) void cvt_bf16_k(
    const float* __restrict__ in, unsigned short* __restrict__ out, int n)
{
  const int i = (blockIdx.x * 256 + threadIdx.x) * 4;
  if (i + 3 < n) {
    const f32x4 v = *(const f32x4*)(in + i);
    us4 o = {f2bf(v[0]), f2bf(v[1]), f2bf(v[2]), f2bf(v[3])};
    *(us4*)(out + i) = o;
  }
}

// --------------------------------------------- f32 [rows][cols] -> bf16 [cols][rows]
__global__ __launch_bounds__(256) void transpose_cvt_k(
    const float* __restrict__ in, unsigned short* __restrict__ out,
    int rows, int cols)
{
  __shared__ unsigned short tile[32][33];
  const int c0 = blockIdx.x * 32, r0 = blockIdx.y * 32;
  const int tx = threadIdx.x & 31, ty = threadIdx.x >> 5;   // ty 0..7
  #pragma unroll
  for (int i = ty; i < 32; i += 8)
    tile[i][tx] = f2bf(in[(size_t)(r0 + i) * cols + (c0 + tx)]);
  __syncthreads();
  #pragma unroll
  for (int i = ty; i < 32; i += 8)
    out[(size_t)(c0 + i) * rows + (r0 + tx)] = tile[tx][i];
}

// ---------------------------------- V columns of qkv -> Vt[bh][d=64][s=2048]
__global__ __launch_bounds__(256) void vt_transpose_k(
    const unsigned short* __restrict__ qkv, unsigned short* __restrict__ vt)
{
  __shared__ unsigned short tile[32][33];
  const int dt = blockIdx.x & 1;           // 2 d-tiles
  const int st = (blockIdx.x >> 1) & 63;   // 64 s-tiles
  const int bh = blockIdx.x >> 7;          // 64 (b,h)
  const int b = bh >> 4, h = bh & 15;
  const int tx = threadIdx.x & 31, ty = threadIdx.x >> 5;
  const int s0 = st * 32, d0 = dt * 32;
  const unsigned short* src = qkv + (size_t)b * NS * N3D + 2 * ND + h * NDH;
  #pragma unroll
  for (int i = ty; i < 32; i += 8)
    tile[i][tx] = src[(size_t)(s0 + i) * N3D + d0 + tx];
  __syncthreads();
  unsigned short* dst = vt + (size_t)bh * NDH * NS;
  #pragma unroll
  for (int i = ty; i < 32; i += 8)
    dst[(size_t)(d0 + i) * NS + s0 + tx] = tile[tx][i];
}

// ------------------------------------------------- GEMM  C = A * Bt^T + bias
// R25: BM=128 x BN=256, 4 waves, EACH WAVE OWNS ALL 128 ROWS x its 64 cols
// (acc[8][4]). Rationale: GEMM1 was pinned at MfmaUtil 26% = the LDS-read-BW
// cap for 64x64-per-wave tiles (12 b128 per 16 MFMA = 32 FLOP/LDS-byte; 85
// B/cy/CU -> 28%). GEMM2 (identical code, clean L2) measured ~42% = the
// 128 B/cy cap. 128x64-per-wave: 12 b128 per 32 MFMA = 42.7 FLOP/B -> cap
// rises 1.33x; stage traffic per FLOP drops 1.5x. 2-phase dbuf + pre-swizzled
// source staging preserved (sc=(t&3)^((t>>3)&3); dest wave-uniform + l*16B
// because (l>>2)*32+(l&3)*8 == 8l; read chunk = lg^((lr>>1)&3): 8 quads x 2
// lanes, conflict-free). SCALE_Q: fold attention's 0.125*log2e into Q cols
// (block-uniform n0+w*64 < 1024) — attn reads Q pre-scaled.
// XCD: square footprint (4m x 2n chiplet grid), bijective.
template<bool OUT_F32, bool SCALE_Q>
__global__ __launch_bounds__(256) void gemm_bt_bias(
    const unsigned short* __restrict__ A,
    const unsigned short* __restrict__ Bt,
    const float* __restrict__ bias,
    unsigned short* __restrict__ Cb,
    float* __restrict__ Cf,
    int M, int N, int K)
{
  __shared__ __align__(16) unsigned short Alds[2][128 * 32];
  __shared__ __align__(16) unsigned short Blds[2][256 * 32];
  const int nbn = N >> 8;              // 256-wide col tiles
  const int nbm = M >> 7;              // 128-high row tiles
  const int xcd = blockIdx.x & 7;
  const int t   = blockIdx.x >> 3;
  const int bnpx = nbn >> 1;           // chiplet grid 4m x 2n
  const int bn  = (xcd & 1) * bnpx + t % bnpx;
  const int bm  = (xcd >> 1) * (nbm >> 2) + t / bnpx;
  const int m0 = bm << 7, n0 = bn << 8;
  const int tid = threadIdx.x;
  const int w = tid >> 6, l = tid & 63;
  const int lr = l & 15, lg = l >> 4;

  // staging: thread t -> row t>>2 (+64i), chunk t&3; source chunk pre-swizzled
  const int sc = (tid & 3) ^ ((tid >> 3) & 3);
  const unsigned short* gA = A + (size_t)(m0 + (tid >> 2)) * K + sc * 8;
  const unsigned short* gB = Bt + (size_t)(n0 + (tid >> 2)) * K + sc * 8;
  const int lbase = 512 * w;           // + 8*l implicit in gld_lds lane offset

  auto stage = [&](int buf, int k0) {
    #pragma unroll
    for (int i = 0; i < 2; ++i)
      GLD16(gA + k0 + (size_t)(64 * i) * K, &Alds[buf][lbase + 2048 * i]);
    #pragma unroll
    for (int i = 0; i < 4; ++i)
      GLD16(gB + k0 + (size_t)(64 * i) * K, &Blds[buf][lbase + 2048 * i]);
  };

  f32x4 acc[8][4] = {};
  const int rch = ((lg ^ ((lr >> 1) & 3)) << 3);   // read-side swizzled chunk

  stage(0, 0);
  __syncthreads();                   // prologue: only exposed stage latency

  #pragma unroll 1
  for (int it = 0; it < (K >> 5); ++it) {
    const int buf = it & 1;
    const int k0 = it << 5;
    if (k0 + 32 < K) stage(buf ^ 1, k0 + 32);   // async; drains at barrier below

    short8 a[8], b[4];
    #pragma unroll
    for (int i = 0; i < 8; ++i)
      a[i] = *(const short8*)(&Alds[buf][(i * 16 + lr) * 32 + rch]);
    #pragma unroll
    for (int j = 0; j < 4; ++j)
      b[j] = *(const short8*)(&Blds[buf][(w * 64 + j * 16 + lr) * 32 + rch]);

    #pragma unroll
    for (int i = 0; i < 8; ++i)
      #pragma unroll
      for (int j = 0; j < 4; ++j)
        acc[i][j] = __builtin_amdgcn_mfma_f32_16x16x32_bf16(a[i], b[j], acc[i][j], 0, 0, 0);

    __syncthreads();   // joins readers of buf + drains stage(buf^1) (landed)
  }

  const float qs = (SCALE_Q && (n0 + w * 64) < ND) ? QSCALE_F : 1.0f;
  #pragma unroll
  for (int j = 0; j < 4; ++j) {
    const int col = n0 + w * 64 + j * 16 + lr;
    const float bv = bias[col];
    #pragma unroll
    for (int i = 0; i < 8; ++i) {
      #pragma unroll
      for (int r = 0; r < 4; ++r) {
        const int row = m0 + i * 16 + lg * 4 + r;
        const float v = (acc[i][j][r] + bv) * qs;
        if (OUT_F32) Cf[(size_t)row * N + col] = v;
        else         Cb[(size_t)row * N + col] = f2bf(v);
      }
    }
  }
}

// ----------------------------------------------------- causal flash attention
// R21 structure (8-wave blocks x 128 q-rows; KVBLK=128 as 2x64-key subtiles,
// 17 barriers/block; pre-swizzled source, 0 bank conflicts; no-max-tracking
// exp2 softmax; T5 setprio). R25: Q arrives PRE-SCALED by 0.125*log2e
// (folded into GEMM1's epilogue) — prologue prescale deleted.
__global__ __launch_bounds__(512) void attn_fwd(
    const unsigned short* __restrict__ qkv,
    const unsigned short* __restrict__ Vt,
    unsigned short* __restrict__ out)
{
  __shared__ __align__(16) char Kl[2][2][64 * 128];  // [buf][subtile][row*128+swz]
  __shared__ __align__(16) char Vl[2][2][64 * 128];  // rows = d, cols = key

  const int bid = blockIdx.x;
  const int bh = bid & 63;               // XCD = bh % 8 stable
  const int slot = bid >> 6;             // 0..7
  const int b = bh >> 4, h = bh & 15;
  const int w = threadIdx.x >> 6, l = threadIdx.x & 63;   // w 0..7
  const int lr = l & 15, lg = l >> 4;

  const size_t rs = N3D;
  const unsigned short* Qb = qkv + (size_t)b * NS * rs + (size_t)h * NDH;
  const unsigned short* Kb = Qb + ND;
  const unsigned short* VtB = Vt + (size_t)bh * NDH * NS;

  const int srow = l >> 3;                               // 0..7
  const int sw = (((l & 7) * 16) ^ (srow << 4)) >> 1;    // element offset
  const unsigned short* KsrcBase = Kb + (size_t)(8 * w + srow) * rs + sw;
  const unsigned short* VsrcBase = VtB + (size_t)(8 * w + srow) * NS + sw;
  const int ldsRow0 = (8 * w) * 128;                     // wave's dest base

  const int ksw = (lr & 7) << 4;               // read-side XOR swizzle

  #pragma unroll 1
  for (int pass = 0; pass < 2; ++pass) {
    const int qt = pass == 0 ? slot : 15 - slot;   // q-tile 0..15 (128 rows)
    const int q0 = qt * 128 + w * 16;              // wave's 16 q-rows
    const int T2 = qt + 1;                         // 128-key tiles this pass

    // Q fragment for rows q0+lr (already scaled by 0.125*log2e upstream)
    short8 qf[2];
    {
      const unsigned short* qrow = Qb + (size_t)(q0 + lr) * rs + lg * 8;
      qf[0] = *(const short8*)(qrow);
      qf[1] = *(const short8*)(qrow + 32);
    }

    float l_run = 0.f;                 // per-lane PARTIAL row sum
    f32x4 o[4] = {};

    auto stage = [&](int buf, int kt2) {
      const int kb = kt2 << 7;
      GLD16(KsrcBase + (size_t)kb * rs,        &Kl[buf][0][ldsRow0]);
      GLD16(KsrcBase + (size_t)(kb + 64) * rs, &Kl[buf][1][ldsRow0]);
      GLD16(VsrcBase + kb,                     &Vl[buf][0][ldsRow0]);
      GLD16(VsrcBase + kb + 64,                &Vl[buf][1][ldsRow0]);
    };

    stage(0, 0);
    __syncthreads();   // compiler drains vmcnt before s_barrier

    #pragma unroll 1
    for (int kt2 = 0; kt2 < T2; ++kt2) {
      const int cur = kt2 & 1;
      if (kt2 + 1 < T2) stage(cur ^ 1, kt2 + 1);   // async, lands by next barrier

      #pragma unroll
      for (int st = 0; st < 2; ++st) {
        const int kbase = kt2 * 128 + st * 64;
        if (kbase > q0 + 15) continue;   // wave-uniform: skip fully-masked

        // K fragments from LDS (swizzled ds_read_b128)
        short8 kf[4][2];
        #pragma unroll
        for (int ks = 0; ks < 4; ++ks) {
          const char* rowp = &Kl[cur][st][(ks * 16 + lr) * 128];
          kf[ks][0] = *(const short8*)(rowp + ((lg * 16) ^ ksw));
          kf[ks][1] = *(const short8*)(rowp + ((64 + lg * 16) ^ ksw));
        }

        // swapped QK^T: s[ks] = S^T[key=kbase+ks*16+lg*4+r][q=q0+lr]
        f32x4 s[4] = {};
        __builtin_amdgcn_s_setprio(1);
        #pragma unroll
        for (int ks = 0; ks < 4; ++ks) {
          s[ks] = __builtin_amdgcn_mfma_f32_16x16x32_bf16(kf[ks][0], qf[0], s[ks], 0, 0, 0);
          s[ks] = __builtin_amdgcn_mfma_f32_16x16x32_bf16(kf[ks][1], qf[1], s[ks], 0, 0, 0);
        }
        __builtin_amdgcn_s_setprio(0);

        // V fragments (ds latency overlaps the softmax VALU below)
        short8 vf[4][2];
        #pragma unroll
        for (int nb = 0; nb < 4; ++nb) {
          const char* rowp = &Vl[cur][st][(nb * 16 + lr) * 128];
          vf[nb][0] = *(const short8*)(rowp + ((lg * 16) ^ ksw));
          vf[nb][1] = *(const short8*)(rowp + ((64 + lg * 16) ^ ksw));
        }

        const bool domask = (kbase + 63 > q0);   // wave-uniform (diag tiles)
        const int qi = q0 + lr;
        // un-shifted exponentials (bounded-score proof, R16); mask -> 0
        float p[16];
        if (domask) {
          #pragma unroll
          for (int ks = 0; ks < 4; ++ks)
            #pragma unroll
            for (int r = 0; r < 4; ++r)
              p[ks * 4 + r] = (kbase + ks * 16 + lg * 4 + r > qi)
                                ? 0.f : exp2f(s[ks][r]);
        } else {
          #pragma unroll
          for (int ks = 0; ks < 4; ++ks)
            #pragma unroll
            for (int r = 0; r < 4; ++r)
              p[ks * 4 + r] = exp2f(s[ks][r]);
        }
        // per-lane PARTIAL row sum (no shuffles; reduced once in epilogue)
        float s0 = (p[0] + p[1]) + (p[2] + p[3]);
        float s1 = (p[4] + p[5]) + (p[6] + p[7]);
        float s2 = (p[8] + p[9]) + (p[10] + p[11]);
        float s3 = (p[12] + p[13]) + (p[14] + p[15]);
        l_run += (s0 + s1) + (s2 + s3);

        // pack P to bf16 pairs: A_ks = keys ks*16+lg*4+{0,1}, B_ks = {2,3}
        unsigned A0 = cvtpk_bf16(p[0],  p[1]),  B0 = cvtpk_bf16(p[2],  p[3]);
        unsigned A1 = cvtpk_bf16(p[4],  p[5]),  B1 = cvtpk_bf16(p[6],  p[7]);
        unsigned A2 = cvtpk_bf16(p[8],  p[9]),  B2 = cvtpk_bf16(p[10], p[11]);
        unsigned A3 = cvtpk_bf16(p[12], p[13]), B3 = cvtpk_bf16(p[14], p[15]);

        // in-register transpose to PV A-fragment layout (VALU, no LDS)
        asm("v_permlane32_swap_b32 %0, %1" : "+v"(A0), "+v"(A1));
        asm("v_permlane16_swap_b32 %0, %1" : "+v"(A0), "+v"(A1));
        asm("v_permlane32_swap_b32 %0, %1" : "+v"(B0), "+v"(B1));
        asm("v_permlane16_swap_b32 %0, %1" : "+v"(B0), "+v"(B1));
        asm("v_permlane32_swap_b32 %0, %1" : "+v"(A2), "+v"(A3));
        asm("v_permlane16_swap_b32 %0, %1" : "+v"(A2), "+v"(A3));
        asm("v_permlane32_swap_b32 %0, %1" : "+v"(B2), "+v"(B3));
        asm("v_permlane16_swap_b32 %0, %1" : "+v"(B2), "+v"(B3));

        uint4v u0 = {A0, B0, A1, B1};   // pf0: keys lg*8+0..7
        uint4v u1 = {A2, B2, A3, B3};   // pf1: keys 32+lg*8+0..7
        short8 pf0 = __builtin_bit_cast(short8, u0);
        short8 pf1 = __builtin_bit_cast(short8, u1);

        __builtin_amdgcn_s_setprio(1);
        #pragma unroll
        for (int nb = 0; nb < 4; ++nb)
          o[nb] = __builtin_amdgcn_mfma_f32_16x16x32_bf16(pf0, vf[nb][0], o[nb], 0, 0, 0);
        #pragma unroll
        for (int nb = 0; nb < 4; ++nb)
          o[nb] = __builtin_amdgcn_mfma_f32_16x16x32_bf16(pf1, vf[nb][1], o[nb], 0, 0, 0);
        __builtin_amdgcn_s_setprio(0);
      }

      __syncthreads();   // joins waves; drains vmcnt (stage done) + LDS reads
    }

    // epilogue: reduce the per-lane l_run partials (once per pass), normalize
    {
      float lt = l_run;
      lt += __shfl_xor(lt, 16);
      lt += __shfl_xor(lt, 32);
      #pragma unroll
      for (int rr = 0; rr < 4; ++rr) {
        const float lq = __shfl(lt, lg * 4 + rr);
        const float inv = 1.0f / lq;
        const int qi = q0 + lg * 4 + rr;
        #pragma unroll
        for (int nb = 0; nb < 4; ++nb)
          out[(size_t)(b * NS + qi) * ND + h * NDH + nb * 16 + lr] = f2bf(o[nb][rr] * inv);
      }
    }
  }
}

// --------------------------------------------------------------------- launch
extern "C" void kernel_launch(void* const* d_in, const int* in_sizes, int n_in,
                              void* d_out, int out_size, void* d_ws, size_t ws_size,
                              hipStream_t stream) {
  const float* x     = (const float*)d_in[0];
  const float* w_in  = (const float*)d_in[1];
  const float* b_in  = (const float*)d_in[2];
  const float* w_out = (const float*)d_in[3];
  const float* b_out = (const float*)d_in[4];
  float* out = (float*)d_out;

  char* ws = (char*)d_ws;
  size_t off = 0;
  unsigned short* x_bf    = (unsigned short*)(ws + off); off += (size_t)NM * ND * 2;    // 16 MiB
  unsigned short* qkv     = (unsigned short*)(ws + off); off += (size_t)NM * N3D * 2;   // 48 MiB
  unsigned short* attn    = (unsigned short*)(ws + off); off += (size_t)NM * ND * 2;    // 16 MiB
  unsigned short* w_in_t  = (unsigned short*)(ws + off); off += (size_t)N3D * ND * 2;   //  6 MiB
  unsigned short* w_out_t = (unsigned short*)(ws + off); off += (size_t)ND * ND * 2;    //  2 MiB
  // Vt aliases x_bf: x_bf is dead after GEMM1, vt_transpose runs after GEMM1.
  unsigned short* vt = x_bf;                                                            // 16 MiB

  // x -> bf16
  cvt_bf16_k<<<dim3((NM * ND) / (256 * 4)), 256, 0, stream>>>(x, x_bf, NM * ND);
  // weight transposes + cast: w[K][N] f32 -> wt[N][K] bf16
  transpose_cvt_k<<<dim3(N3D / 32, ND / 32), 256, 0, stream>>>(w_in, w_in_t, ND, N3D);
  transpose_cvt_k<<<dim3(ND / 32, ND / 32), 256, 0, stream>>>(w_out, w_out_t, ND, ND);

  // qkv = x @ w_in + b_in  (bf16 out; Q columns pre-scaled by 0.125*log2e)
  gemm_bt_bias<false, true><<<dim3((NM / 128) * (N3D / 256)), 256, 0, stream>>>(
      x_bf, w_in_t, b_in, qkv, nullptr, NM, N3D, ND);

  // V -> Vt (transposed per head)
  vt_transpose_k<<<dim3(64 * 64 * 2), 256, 0, stream>>>(qkv, vt);

  // attention: 512 blocks x 512 threads (8 waves, 128 q-rows; pairing qt/15-qt)
  attn_fwd<<<dim3(64 * 8), 512, 0, stream>>>(qkv, vt, attn);

  // out = attn @ w_out + b_out       (f32 out)
  gemm_bt_bias<true, false><<<dim3((NM / 128) * (ND / 256)), 256, 0, stream>>>(
      attn, w_out_t, b_out, nullptr, out, NM, ND, ND);
}

// Round 26
// 178.201 us; speedup vs baseline: 1.3293x; 1.3293x over previous
//
#include <hip/hip_runtime.h>
#include <hip/hip_bf16.h>
#include <cstdint>

#define NB 4
#define NS 2048
#define ND 1024
#define NH 16
#define NDH 64
#define NM (NB*NS)       // 8192
#define N3D (3*ND)       // 3072

typedef __attribute__((ext_vector_type(8))) short short8;
typedef __attribute__((ext_vector_type(4))) float f32x4;
typedef __attribute__((ext_vector_type(4))) unsigned short us4;
typedef __attribute__((ext_vector_type(4))) unsigned int uint4v;

__device__ __forceinline__ float bf2f(unsigned short u) {
  unsigned int i = ((unsigned int)u) << 16;
  return __builtin_bit_cast(float, i);
}
__device__ __forceinline__ unsigned short f2bf(float f) {
  unsigned int i = __builtin_bit_cast(unsigned int, f);
  i = (i + 0x7FFFu + ((i >> 16) & 1u)) >> 16;
  return (unsigned short)i;
}
// packed 2x bf16 (RNE) from two f32 — T12 recipe, no builtin on gfx950
__device__ __forceinline__ unsigned int cvtpk_bf16(float lo, float hi) {
  unsigned int r;
  asm("v_cvt_pk_bf16_f32 %0, %1, %2" : "=v"(r) : "v"(lo), "v"(hi));
  return r;
}

#define GLD16(g, l) __builtin_amdgcn_global_load_lds( \
    (__attribute__((address_space(1))) void*)(void*)(g), \
    (__attribute__((address_space(3))) void*)(l), 16, 0, 0)

#define QSCALE_F (0.125f * 1.44269504f)   // exp2-domain attention scale

// ------------------------------------------------------------ f32 -> bf16 cast
__global__ __launch_bounds__(256) void cvt_bf16_k(
    const float* __restrict__ in, unsigned short* __restrict__ out, int n)
{
  const int i = (blockIdx.x * 256 + threadIdx.x) * 4;
  if (i + 3 < n) {
    const f32x4 v = *(const f32x4*)(in + i);
    us4 o = {f2bf(v[0]), f2bf(v[1]), f2bf(v[2]), f2bf(v[3])};
    *(us4*)(out + i) = o;
  }
}

// --------------------------------------------- f32 [rows][cols] -> bf16 [cols][rows]
__global__ __launch_bounds__(256) void transpose_cvt_k(
    const float* __restrict__ in, unsigned short* __restrict__ out,
    int rows, int cols)
{
  __shared__ unsigned short tile[32][33];
  const int c0 = blockIdx.x * 32, r0 = blockIdx.y * 32;
  const int tx = threadIdx.x & 31, ty = threadIdx.x >> 5;   // ty 0..7
  #pragma unroll
  for (int i = ty; i < 32; i += 8)
    tile[i][tx] = f2bf(in[(size_t)(r0 + i) * cols + (c0 + tx)]);
  __syncthreads();
  #pragma unroll
  for (int i = ty; i < 32; i += 8)
    out[(size_t)(c0 + i) * rows + (r0 + tx)] = tile[tx][i];
}

// ---------------------------------- V columns of qkv -> Vt[bh][d=64][s=2048]
__global__ __launch_bounds__(256) void vt_transpose_k(
    const unsigned short* __restrict__ qkv, unsigned short* __restrict__ vt)
{
  __shared__ unsigned short tile[32][33];
  const int dt = blockIdx.x & 1;           // 2 d-tiles
  const int st = (blockIdx.x >> 1) & 63;   // 64 s-tiles
  const int bh = blockIdx.x >> 7;          // 64 (b,h)
  const int b = bh >> 4, h = bh & 15;
  const int tx = threadIdx.x & 31, ty = threadIdx.x >> 5;
  const int s0 = st * 32, d0 = dt * 32;
  const unsigned short* src = qkv + (size_t)b * NS * N3D + 2 * ND + h * NDH;
  #pragma unroll
  for (int i = ty; i < 32; i += 8)
    tile[i][tx] = src[(size_t)(s0 + i) * N3D + d0 + tx];
  __syncthreads();
  unsigned short* dst = vt + (size_t)bh * NDH * NS;
  #pragma unroll
  for (int i = ty; i < 32; i += 8)
    dst[(size_t)(d0 + i) * NS + s0 + tx] = tile[tx][i];
}

// ------------------------------------------------- GEMM  C = A * Bt^T + bias
// RESTORED R24 (best measured config): 128x128 tile, BK=64, 4 waves (2x2 of
// 64x64), dbuf LDS + one barrier per K-step, 8-quad bank swizzle
// (chunk ^= row&7 via pre-swizzled source; read chunk=(kk*4+lg)^(lr&7)),
// square per-XCD L2 footprint (chiplet grid 4m x 2n). At the 2-phase
// structural ceiling for K=1024 (~640 TF, m248 reference). R25's 128x256
// acc[8][4] spilled (VGPR 164 + 32MB scratch writes) — reverted.
// SCALE_Q: fold attention's 0.125*log2e into Q columns (col < 1024;
// block-uniform per (n0,wc) since tiles are 64-col aligned).
template<bool OUT_F32, bool SCALE_Q>
__global__ __launch_bounds__(256) void gemm_bt_bias(
    const unsigned short* __restrict__ A,
    const unsigned short* __restrict__ Bt,
    const float* __restrict__ bias,
    unsigned short* __restrict__ Cb,
    float* __restrict__ Cf,
    int M, int N, int K)
{
  __shared__ __align__(16) unsigned short Alds[2][128 * 64];
  __shared__ __align__(16) unsigned short Blds[2][128 * 64];
  const int nbn = N >> 7;
  const int nbm = M >> 7;
  const int xcd = blockIdx.x & 7;
  const int t   = blockIdx.x >> 3;
  const int bnpx = nbn >> 1;           // chiplet grid 4m x 2n
  const int bn  = (xcd & 1) * bnpx + t % bnpx;
  const int bm  = (xcd >> 1) * (nbm >> 2) + t / bnpx;
  const int m0 = bm << 7, n0 = bn << 7;
  const int w = threadIdx.x >> 6, l = threadIdx.x & 63;
  const int wr = w >> 1, wc = w & 1;
  const int lr = l & 15, lg = l >> 4;

  // staging: lane l -> rows w*32+(l>>3)+{0,8,16,24}, chunk l&7 (of 8);
  // source chunk pre-swizzled by row&7 so linear LDS writes land swizzled.
  const int sc = (l & 7) ^ (l >> 3);
  const unsigned short* gA = A + (size_t)(m0 + w * 32 + (l >> 3)) * K + sc * 8;
  const unsigned short* gB = Bt + (size_t)(n0 + w * 32 + (l >> 3)) * K + sc * 8;
  const int lwoff = (w * 32) * 64;   // wave's element offset in the tile

  auto stage = [&](int buf, int k0) {
    unsigned short* la = &Alds[buf][lwoff];
    unsigned short* lb = &Blds[buf][lwoff];
    #pragma unroll
    for (int r = 0; r < 4; ++r) {
      GLD16(gA + k0 + (size_t)(8 * r) * K, la + (8 * r) * 64);
      GLD16(gB + k0 + (size_t)(8 * r) * K, lb + (8 * r) * 64);
    }
  };

  f32x4 acc[4][4] = {};
  const int rxor = lr & 7;           // read-side XOR (row&7 == lr&7)

  stage(0, 0);
  __syncthreads();                   // prologue: only exposed stage latency

  #pragma unroll 1
  for (int it = 0; it < (K >> 6); ++it) {
    const int buf = it & 1;
    const int k0 = it << 6;
    if (k0 + 64 < K) stage(buf ^ 1, k0 + 64);   // async; drains at barrier below

    #pragma unroll
    for (int kk = 0; kk < 2; ++kk) {
      const int rch = ((kk * 4 + lg) ^ rxor) << 3;
      short8 a[4], b[4];
      #pragma unroll
      for (int i = 0; i < 4; ++i)
        a[i] = *(const short8*)(&Alds[buf][(wr * 64 + i * 16 + lr) * 64 + rch]);
      #pragma unroll
      for (int j = 0; j < 4; ++j)
        b[j] = *(const short8*)(&Blds[buf][(wc * 64 + j * 16 + lr) * 64 + rch]);

      #pragma unroll
      for (int i = 0; i < 4; ++i)
        #pragma unroll
        for (int j = 0; j < 4; ++j)
          acc[i][j] = __builtin_amdgcn_mfma_f32_16x16x32_bf16(a[i], b[j], acc[i][j], 0, 0, 0);
    }

    __syncthreads();   // joins readers of buf + drains stage(buf^1) (landed)
  }

  const float qs = (SCALE_Q && (n0 + wc * 64) < ND) ? QSCALE_F : 1.0f;
  #pragma unroll
  for (int j = 0; j < 4; ++j) {
    const int col = n0 + wc * 64 + j * 16 + lr;
    const float bv = bias[col];
    #pragma unroll
    for (int i = 0; i < 4; ++i) {
      #pragma unroll
      for (int r = 0; r < 4; ++r) {
        const int row = m0 + wr * 64 + i * 16 + lg * 4 + r;
        const float v = (acc[i][j][r] + bv) * qs;
        if (OUT_F32) Cf[(size_t)row * N + col] = v;
        else         Cb[(size_t)row * N + col] = f2bf(v);
      }
    }
  }
}

// ----------------------------------------------------- causal flash attention
// R21 structure (8-wave blocks x 128 q-rows; KVBLK=128 as 2x64-key subtiles,
// 17 barriers/block; pre-swizzled source, 0 bank conflicts; no-max-tracking
// exp2 softmax; T5 setprio). Q arrives PRE-SCALED by 0.125*log2e (folded
// into GEMM1's epilogue).
__global__ __launch_bounds__(512) void attn_fwd(
    const unsigned short* __restrict__ qkv,
    const unsigned short* __restrict__ Vt,
    unsigned short* __restrict__ out)
{
  __shared__ __align__(16) char Kl[2][2][64 * 128];  // [buf][subtile][row*128+swz]
  __shared__ __align__(16) char Vl[2][2][64 * 128];  // rows = d, cols = key

  const int bid = blockIdx.x;
  const int bh = bid & 63;               // XCD = bh % 8 stable
  const int slot = bid >> 6;             // 0..7
  const int b = bh >> 4, h = bh & 15;
  const int w = threadIdx.x >> 6, l = threadIdx.x & 63;   // w 0..7
  const int lr = l & 15, lg = l >> 4;

  const size_t rs = N3D;
  const unsigned short* Qb = qkv + (size_t)b * NS * rs + (size_t)h * NDH;
  const unsigned short* Kb = Qb + ND;
  const unsigned short* VtB = Vt + (size_t)bh * NDH * NS;

  const int srow = l >> 3;                               // 0..7
  const int sw = (((l & 7) * 16) ^ (srow << 4)) >> 1;    // element offset
  const unsigned short* KsrcBase = Kb + (size_t)(8 * w + srow) * rs + sw;
  const unsigned short* VsrcBase = VtB + (size_t)(8 * w + srow) * NS + sw;
  const int ldsRow0 = (8 * w) * 128;                     // wave's dest base

  const int ksw = (lr & 7) << 4;               // read-side XOR swizzle

  #pragma unroll 1
  for (int pass = 0; pass < 2; ++pass) {
    const int qt = pass == 0 ? slot : 15 - slot;   // q-tile 0..15 (128 rows)
    const int q0 = qt * 128 + w * 16;              // wave's 16 q-rows
    const int T2 = qt + 1;                         // 128-key tiles this pass

    // Q fragment for rows q0+lr (already scaled by 0.125*log2e upstream)
    short8 qf[2];
    {
      const unsigned short* qrow = Qb + (size_t)(q0 + lr) * rs + lg * 8;
      qf[0] = *(const short8*)(qrow);
      qf[1] = *(const short8*)(qrow + 32);
    }

    float l_run = 0.f;                 // per-lane PARTIAL row sum
    f32x4 o[4] = {};

    auto stage = [&](int buf, int kt2) {
      const int kb = kt2 << 7;
      GLD16(KsrcBase + (size_t)kb * rs,        &Kl[buf][0][ldsRow0]);
      GLD16(KsrcBase + (size_t)(kb + 64) * rs, &Kl[buf][1][ldsRow0]);
      GLD16(VsrcBase + kb,                     &Vl[buf][0][ldsRow0]);
      GLD16(VsrcBase + kb + 64,                &Vl[buf][1][ldsRow0]);
    };

    stage(0, 0);
    __syncthreads();   // compiler drains vmcnt before s_barrier

    #pragma unroll 1
    for (int kt2 = 0; kt2 < T2; ++kt2) {
      const int cur = kt2 & 1;
      if (kt2 + 1 < T2) stage(cur ^ 1, kt2 + 1);   // async, lands by next barrier

      #pragma unroll
      for (int st = 0; st < 2; ++st) {
        const int kbase = kt2 * 128 + st * 64;
        if (kbase > q0 + 15) continue;   // wave-uniform: skip fully-masked

        // K fragments from LDS (swizzled ds_read_b128)
        short8 kf[4][2];
        #pragma unroll
        for (int ks = 0; ks < 4; ++ks) {
          const char* rowp = &Kl[cur][st][(ks * 16 + lr) * 128];
          kf[ks][0] = *(const short8*)(rowp + ((lg * 16) ^ ksw));
          kf[ks][1] = *(const short8*)(rowp + ((64 + lg * 16) ^ ksw));
        }

        // swapped QK^T: s[ks] = S^T[key=kbase+ks*16+lg*4+r][q=q0+lr]
        f32x4 s[4] = {};
        __builtin_amdgcn_s_setprio(1);
        #pragma unroll
        for (int ks = 0; ks < 4; ++ks) {
          s[ks] = __builtin_amdgcn_mfma_f32_16x16x32_bf16(kf[ks][0], qf[0], s[ks], 0, 0, 0);
          s[ks] = __builtin_amdgcn_mfma_f32_16x16x32_bf16(kf[ks][1], qf[1], s[ks], 0, 0, 0);
        }
        __builtin_amdgcn_s_setprio(0);

        // V fragments (ds latency overlaps the softmax VALU below)
        short8 vf[4][2];
        #pragma unroll
        for (int nb = 0; nb < 4; ++nb) {
          const char* rowp = &Vl[cur][st][(nb * 16 + lr) * 128];
          vf[nb][0] = *(const short8*)(rowp + ((lg * 16) ^ ksw));
          vf[nb][1] = *(const short8*)(rowp + ((64 + lg * 16) ^ ksw));
        }

        const bool domask = (kbase + 63 > q0);   // wave-uniform (diag tiles)
        const int qi = q0 + lr;
        // un-shifted exponentials (bounded-score proof, R16); mask -> 0
        float p[16];
        if (domask) {
          #pragma unroll
          for (int ks = 0; ks < 4; ++ks)
            #pragma unroll
            for (int r = 0; r < 4; ++r)
              p[ks * 4 + r] = (kbase + ks * 16 + lg * 4 + r > qi)
                                ? 0.f : exp2f(s[ks][r]);
        } else {
          #pragma unroll
          for (int ks = 0; ks < 4; ++ks)
            #pragma unroll
            for (int r = 0; r < 4; ++r)
              p[ks * 4 + r] = exp2f(s[ks][r]);
        }
        // per-lane PARTIAL row sum (no shuffles; reduced once in epilogue)
        float s0 = (p[0] + p[1]) + (p[2] + p[3]);
        float s1 = (p[4] + p[5]) + (p[6] + p[7]);
        float s2 = (p[8] + p[9]) + (p[10] + p[11]);
        float s3 = (p[12] + p[13]) + (p[14] + p[15]);
        l_run += (s0 + s1) + (s2 + s3);

        // pack P to bf16 pairs: A_ks = keys ks*16+lg*4+{0,1}, B_ks = {2,3}
        unsigned A0 = cvtpk_bf16(p[0],  p[1]),  B0 = cvtpk_bf16(p[2],  p[3]);
        unsigned A1 = cvtpk_bf16(p[4],  p[5]),  B1 = cvtpk_bf16(p[6],  p[7]);
        unsigned A2 = cvtpk_bf16(p[8],  p[9]),  B2 = cvtpk_bf16(p[10], p[11]);
        unsigned A3 = cvtpk_bf16(p[12], p[13]), B3 = cvtpk_bf16(p[14], p[15]);

        // in-register transpose to PV A-fragment layout (VALU, no LDS)
        asm("v_permlane32_swap_b32 %0, %1" : "+v"(A0), "+v"(A1));
        asm("v_permlane16_swap_b32 %0, %1" : "+v"(A0), "+v"(A1));
        asm("v_permlane32_swap_b32 %0, %1" : "+v"(B0), "+v"(B1));
        asm("v_permlane16_swap_b32 %0, %1" : "+v"(B0), "+v"(B1));
        asm("v_permlane32_swap_b32 %0, %1" : "+v"(A2), "+v"(A3));
        asm("v_permlane16_swap_b32 %0, %1" : "+v"(A2), "+v"(A3));
        asm("v_permlane32_swap_b32 %0, %1" : "+v"(B2), "+v"(B3));
        asm("v_permlane16_swap_b32 %0, %1" : "+v"(B2), "+v"(B3));

        uint4v u0 = {A0, B0, A1, B1};   // pf0: keys lg*8+0..7
        uint4v u1 = {A2, B2, A3, B3};   // pf1: keys 32+lg*8+0..7
        short8 pf0 = __builtin_bit_cast(short8, u0);
        short8 pf1 = __builtin_bit_cast(short8, u1);

        __builtin_amdgcn_s_setprio(1);
        #pragma unroll
        for (int nb = 0; nb < 4; ++nb)
          o[nb] = __builtin_amdgcn_mfma_f32_16x16x32_bf16(pf0, vf[nb][0], o[nb], 0, 0, 0);
        #pragma unroll
        for (int nb = 0; nb < 4; ++nb)
          o[nb] = __builtin_amdgcn_mfma_f32_16x16x32_bf16(pf1, vf[nb][1], o[nb], 0, 0, 0);
        __builtin_amdgcn_s_setprio(0);
      }

      __syncthreads();   // joins waves; drains vmcnt (stage done) + LDS reads
    }

    // epilogue: reduce the per-lane l_run partials (once per pass), normalize
    {
      float lt = l_run;
      lt += __shfl_xor(lt, 16);
      lt += __shfl_xor(lt, 32);
      #pragma unroll
      for (int rr = 0; rr < 4; ++rr) {
        const float lq = __shfl(lt, lg * 4 + rr);
        const float inv = 1.0f / lq;
        const int qi = q0 + lg * 4 + rr;
        #pragma unroll
        for (int nb = 0; nb < 4; ++nb)
          out[(size_t)(b * NS + qi) * ND + h * NDH + nb * 16 + lr] = f2bf(o[nb][rr] * inv);
      }
    }
  }
}

// --------------------------------------------------------------------- launch
extern "C" void kernel_launch(void* const* d_in, const int* in_sizes, int n_in,
                              void* d_out, int out_size, void* d_ws, size_t ws_size,
                              hipStream_t stream) {
  const float* x     = (const float*)d_in[0];
  const float* w_in  = (const float*)d_in[1];
  const float* b_in  = (const float*)d_in[2];
  const float* w_out = (const float*)d_in[3];
  const float* b_out = (const float*)d_in[4];
  float* out = (float*)d_out;

  char* ws = (char*)d_ws;
  size_t off = 0;
  unsigned short* x_bf    = (unsigned short*)(ws + off); off += (size_t)NM * ND * 2;    // 16 MiB
  unsigned short* qkv     = (unsigned short*)(ws + off); off += (size_t)NM * N3D * 2;   // 48 MiB
  unsigned short* attn    = (unsigned short*)(ws + off); off += (size_t)NM * ND * 2;    // 16 MiB
  unsigned short* w_in_t  = (unsigned short*)(ws + off); off += (size_t)N3D * ND * 2;   //  6 MiB
  unsigned short* w_out_t = (unsigned short*)(ws + off); off += (size_t)ND * ND * 2;    //  2 MiB
  // Vt aliases x_bf: x_bf is dead after GEMM1, vt_transpose runs after GEMM1.
  unsigned short* vt = x_bf;                                                            // 16 MiB

  // x -> bf16
  cvt_bf16_k<<<dim3((NM * ND) / (256 * 4)), 256, 0, stream>>>(x, x_bf, NM * ND);
  // weight transposes + cast: w[K][N] f32 -> wt[N][K] bf16
  transpose_cvt_k<<<dim3(N3D / 32, ND / 32), 256, 0, stream>>>(w_in, w_in_t, ND, N3D);
  transpose_cvt_k<<<dim3(ND / 32, ND / 32), 256, 0, stream>>>(w_out, w_out_t, ND, ND);

  // qkv = x @ w_in + b_in  (bf16 out; Q columns pre-scaled by 0.125*log2e)
  gemm_bt_bias<false, true><<<dim3((NM / 128) * (N3D / 128)), 256, 0, stream>>>(
      x_bf, w_in_t, b_in, qkv, nullptr, NM, N3D, ND);

  // V -> Vt (transposed per head)
  vt_transpose_k<<<dim3(64 * 64 * 2), 256, 0, stream>>>(qkv, vt);

  // attention: 512 blocks x 512 threads (8 waves, 128 q-rows; pairing qt/15-qt)
  attn_fwd<<<dim3(64 * 8), 512, 0, stream>>>(qkv, vt, attn);

  // out = attn @ w_out + b_out       (f32 out)
  gemm_bt_bias<true, false><<<dim3((NM / 128) * (ND / 128)), 256, 0, stream>>>(
      attn, w_out_t, b_out, nullptr, out, NM, ND, ND);
}